// Round 3
// baseline (105.854 us; speedup 1.0000x reference)
//
#include <hip/hip_runtime.h>
#include <cfloat>

#define NB 16
#define NC 32
#define NX 48
#define NY 48
#define NZ 48
#define YZ (NY*NZ)          // 2304
#define XYZ (NX*NY*NZ)      // 110592
#define SUM_NUM 56623104.0  // 16*32*110592
#define V 256               // voxels per LDS tile
#define T 4                 // tiles per block
#define PB 108              // blocks per batch sample (108*4*256 = 110592)
#define GRID (NB*PB)        // 1728

// per-block, per-channel partials (fields are [c]-arrays for coalesced finalize reads)
struct BP {
  float vs[NC], s0[NC], sx[NC], sy[NC], sq2[NC], mx[NC];
  int   mi[NC];
};
struct Ws {
  BP    bp[GRID];
  float ab[GRID][2];   // per-block div partials: A = sum sq*mo^2, B = sum sq*mo
};

typedef const __attribute__((address_space(1))) void* gas_t;
typedef __attribute__((address_space(3))) void* las_t;

__global__ __launch_bounds__(256) void k_fused(const float* __restrict__ f,
                                               Ws* __restrict__ ws) {
  const int bb = blockIdx.x / PB;
  const int pb = blockIdx.x % PB;
  const int t  = threadIdx.x;
  const int w  = t >> 6;        // wave 0..3
  const int l  = t & 63;        // lane
  const int g0 = pb * (T * V);  // this block's voxel base within (b,*)

  __shared__ float tile[NC][V];          // 32 KB
  __shared__ float rA[4], rB[4];

  const float* gb = f + (size_t)bb * NC * XYZ;

  // per-channel accumulators: wave w owns channels 8w..8w+7 (slot k)
  float vsK[8], s0K[8], sxK[8], syK[8], sq2K[8], mvK[8];
  int   miK[8];
#pragma unroll
  for (int k = 0; k < 8; ++k) {
    vsK[k] = 0.f; s0K[k] = 0.f; sxK[k] = 0.f; syK[k] = 0.f; sq2K[k] = 0.f;
    mvK[k] = -FLT_MAX; miK[k] = 0;
  }
  float A = 0.f, Bv = 0.f;     // div moments (per-voxel top-2 based)

  for (int tau = 0; tau < T; ++tau) {
    const int gt = g0 + tau * V;

    // ---- stage tile: wave w async-loads its 8 channel rows (1 KB each) ----
    {
      const float* gl = gb + gt + l * 4;
#pragma unroll
      for (int k = 0; k < 8; ++k) {
        const int c = w * 8 + k;
        __builtin_amdgcn_global_load_lds((gas_t)(gl + (size_t)c * XYZ),
                                         (las_t)&tile[c][0], 16, 0, 0);
      }
    }
    __syncthreads();   // drains vmcnt before reads

    // ---- phase 1: per-voxel (column t) top-2 over 32 channels ----
    {
      float m1 = -FLT_MAX, m2 = -FLT_MAX, s0v = 0.f;
#pragma unroll
      for (int c = 0; c < NC; ++c) {
        const float x = tile[c][t];
        s0v = fmaf(x, x, s0v);
        if (x > m1) { m2 = m1; m1 = x; } else if (x > m2) m2 = x;
      }
      const float q1 = m1 * m1;
      const float rest = s0v - q1;           // sum sq over non-arg channels
      A  += q1 * rest + m2 * m2 * q1;
      Bv += m1 * rest + m2 * q1;
    }

    // ---- phase 2: per-channel moments; lane l covers voxels l+64i ----
    {
      float xf[4], yf[4], r2[4]; int gi[4];
#pragma unroll
      for (int i = 0; i < 4; ++i) {
        const int g   = gt + l + 64 * i;
        const int xi  = g / YZ;
        const int rem = g - xi * YZ;
        const int yi  = rem / NZ;
        xf[i] = (float)xi; yf[i] = (float)yi;
        r2[i] = xf[i] * xf[i] + yf[i] * yf[i];
        gi[i] = g;
      }
#pragma unroll
      for (int k = 0; k < 8; ++k) {
        const int c = w * 8 + k;
#pragma unroll
        for (int i = 0; i < 4; ++i) {
          const float x  = tile[c][l + 64 * i];
          const float sq = x * x;
          vsK[k] += x;
          s0K[k] += sq;
          sxK[k]  = fmaf(sq, xf[i], sxK[k]);
          syK[k]  = fmaf(sq, yf[i], syK[k]);
          sq2K[k] = fmaf(sq, r2[i], sq2K[k]);
          // idx increases monotonically per lane across i and tau -> strict '>'
          if (x > mvK[k]) { mvK[k] = x; miK[k] = gi[i]; }
        }
      }
    }
    __syncthreads();   // tile reused next iteration
  }

  // ---- per-wave reduce each owned channel, write block partials ----
  BP* bp = &ws->bp[blockIdx.x];
#pragma unroll
  for (int k = 0; k < 8; ++k) {
    float vs = vsK[k], s0 = s0K[k], sx = sxK[k], sy = syK[k], s2 = sq2K[k];
    float mv = mvK[k]; int mi = miK[k];
    for (int off = 32; off > 0; off >>= 1) {
      vs += __shfl_down(vs, off);
      s0 += __shfl_down(s0, off);
      sx += __shfl_down(sx, off);
      sy += __shfl_down(sy, off);
      s2 += __shfl_down(s2, off);
      const float ov = __shfl_down(mv, off);
      const int   oi = __shfl_down(mi, off);
      if (ov > mv || (ov == mv && oi < mi)) { mv = ov; mi = oi; }  // first occurrence
    }
    if (l == 0) {
      const int c = w * 8 + k;
      bp->vs[c] = vs; bp->s0[c] = s0; bp->sx[c] = sx; bp->sy[c] = sy;
      bp->sq2[c] = s2; bp->mx[c] = mv; bp->mi[c] = mi;
    }
  }

  // ---- block reduce A, B ----
  for (int off = 32; off > 0; off >>= 1) {
    A  += __shfl_down(A,  off);
    Bv += __shfl_down(Bv, off);
  }
  if (l == 0) { rA[w] = A; rB[w] = Bv; }
  __syncthreads();
  if (t == 0) {
    ws->ab[blockIdx.x][0] = (rA[0] + rA[1]) + (rA[2] + rA[3]);
    ws->ab[blockIdx.x][1] = (rB[0] + rB[1]) + (rB[2] + rB[3]);
  }
}

// ---- finalize: merge 108 partials per (b,c), assemble both scalars in f64 ----
__global__ __launch_bounds__(512) void k_fin(const Ws* __restrict__ ws,
                                             float* __restrict__ out) {
  const int t = threadIdx.x;
  const int b = t >> 5, c = t & 31;
  double vs = 0, s0 = 0, sx = 0, sy = 0, s2 = 0;
  float mv = -FLT_MAX; int mi = 0x7fffffff;
  for (int k = 0; k < PB; ++k) {
    const BP* p = &ws->bp[b * PB + k];
    vs += p->vs[c]; s0 += p->s0[c]; sx += p->sx[c]; sy += p->sy[c]; s2 += p->sq2[c];
    const float ov = p->mx[c]; const int oi = p->mi[c];
    if (ov > mv || (ov == mv && oi < mi)) { mv = ov; mi = oi; }
  }
  const double mx = (double)(mi / YZ);
  const double my = (double)((mi / NZ) % NY);
  const double mz = (double)(mi % NZ);
  double dis = s2 - 2.0 * mx * sx - 2.0 * my * sy + (mx * mx + my * my) * s0
             + 2304.0 * (48.0 * mz * mz - 2256.0 * mz + 35720.0);
  double a = 0.0, bb = 0.0;
  for (int i = t; i < GRID; i += 512) { a += ws->ab[i][0]; bb += ws->ab[i][1]; }

  for (int off = 32; off > 0; off >>= 1) {
    dis += __shfl_down(dis, off);
    vs  += __shfl_down(vs,  off);
    s0  += __shfl_down(s0,  off);
    a   += __shfl_down(a,   off);
    bb  += __shfl_down(bb,  off);
  }
  __shared__ double sd[8][5];
  const int wid = t >> 6;
  if ((t & 63) == 0) { sd[wid][0] = dis; sd[wid][1] = vs; sd[wid][2] = s0; sd[wid][3] = a; sd[wid][4] = bb; }
  __syncthreads();
  if (t == 0) {
    for (int wq = 1; wq < 8; ++wq) {
      dis += sd[wq][0]; vs += sd[wq][1]; s0 += sd[wq][2]; a += sd[wq][3]; bb += sd[wq][4];
    }
    const double mgr = vs / SUM_NUM;
    out[0] = (float)(dis / SUM_NUM);
    out[1] = (float)((a - 2.0 * mgr * bb + mgr * mgr * s0) / SUM_NUM);
  }
}

extern "C" void kernel_launch(void* const* d_in, const int* in_sizes, int n_in,
                              void* d_out, int out_size, void* d_ws, size_t ws_size,
                              hipStream_t stream) {
  const float* f = (const float*)d_in[0];
  Ws* ws = (Ws*)d_ws;
  float* out = (float*)d_out;
  hipLaunchKernelGGL(k_fused, dim3(GRID), dim3(256), 0, stream, f, ws);
  hipLaunchKernelGGL(k_fin,   dim3(1),    dim3(512), 0, stream, ws, out);
}

// Round 4
// 98.574 us; speedup vs baseline: 1.0739x; 1.0739x over previous
//
#include <hip/hip_runtime.h>
#include <cfloat>
#include <climits>

#define NB 16
#define NC 32
#define NX 48
#define NY 48
#define NZ 48
#define YZ (NY*NZ)          // 2304
#define XYZ (NX*NY*NZ)      // 110592
#define SUM_NUM 56623104.0  // 16*32*110592
#define V 256               // voxels per LDS tile
#define T 9                 // tiles per block -> 2304 voxels = exactly one x-slab
#define BPS 48              // blocks per sample == NX; block pb owns x == pb
#define GRID (NB*BPS)       // 768

struct BP {
  float s0[NC], sy[NC], syy[NC], mx[NC];
  int   mi[NC];
};
struct Ws {
  BP    bp[GRID];
  float abv[GRID][3];   // A = sum sq*mo^2, B = sum sq*mo, vs = sum v
};

typedef const __attribute__((address_space(1))) void* gas_t;
typedef __attribute__((address_space(3))) void* las_t;

// Stage tile `tau` of this block's slab into buf[d]: wave w loads its 8
// channel rows, one global_load_lds (1 KB: 64 lanes x 16 B) per row.
// => exactly 8 VMEM ops per wave per stage (vmcnt accounting below).
#define STAGE(d, tau) do {                                                   \
    const float* _s = gbase + (size_t)(w * 8) * XYZ + (tau) * V + l * 4;     \
    _Pragma("unroll")                                                        \
    for (int _k = 0; _k < 8; ++_k)                                           \
      __builtin_amdgcn_global_load_lds((gas_t)(_s + (size_t)_k * XYZ),       \
                                       (las_t)&buf[d][w * 8 + _k][0],        \
                                       16, 0, 0);                            \
  } while (0)

__global__ __launch_bounds__(256) void k_fused(const float* __restrict__ f,
                                               Ws* __restrict__ ws) {
  const int bb = blockIdx.x / BPS;
  const int pb = blockIdx.x % BPS;   // also the x index of this block's slab
  const int t  = threadIdx.x;
  const int w  = t >> 6;
  const int l  = t & 63;

  __shared__ float buf[2][NC][V];    // 64 KB double buffer
  __shared__ float r3[4][3];

  const float* gbase = f + (size_t)bb * NC * XYZ + pb * YZ;

  // per-channel accumulators: wave w owns channels 8w..8w+7
  float s0K[8], syK[8], syyK[8], mvK[8];
  int   miK[8];
#pragma unroll
  for (int k = 0; k < 8; ++k) {
    s0K[k] = 0.f; syK[k] = 0.f; syyK[k] = 0.f; mvK[k] = -FLT_MAX; miK[k] = 0;
  }
  float A = 0.f, Bv = 0.f, vs = 0.f;

  STAGE(0, 0);                                   // prologue prefetch
  for (int tau = 0; tau < T; ++tau) {
    const int cur = tau & 1;
    if (tau + 1 < T) {
      STAGE(cur ^ 1, tau + 1);                   // 8 more loads in flight
      asm volatile("s_waitcnt vmcnt(8)" ::: "memory");   // tau's 8 oldest done
    } else {
      asm volatile("s_waitcnt vmcnt(0)" ::: "memory");
    }
    __builtin_amdgcn_s_barrier();                // raw: no vmcnt(0) drain

    const float (*tile)[V] = buf[cur];

    // ---- phase 1: per-voxel (column t) top-2 over 32 channels ----
    {
      float m1 = -FLT_MAX, m2 = -FLT_MAX, s0v = 0.f;
#pragma unroll
      for (int c = 0; c < NC; ++c) {
        const float x = tile[c][t];
        vs += x;
        s0v = fmaf(x, x, s0v);
        if (x > m1) { m2 = m1; m1 = x; } else if (x > m2) m2 = x;
      }
      const float q1 = m1 * m1, rest = s0v - q1;
      A  += q1 * rest + m2 * m2 * q1;
      Bv += m1 * rest + m2 * q1;
    }

    // ---- phase 2: per-channel moments; lane l owns voxels 4l..4l+3 ----
    {
      const int local = tau * V + 4 * l;          // voxel in slab [0,2304)
      const float yf = (float)(local / NZ);       // < 48: same row for all 4
#pragma unroll
      for (int k = 0; k < 8; ++k) {
        const int c = w * 8 + k;
        const float4 v = *(const float4*)&tile[c][4 * l];   // ds_read_b128
        const float s0t = (v.x*v.x + v.y*v.y) + (v.z*v.z + v.w*v.w);
        s0K[k] += s0t;
        syK[k]  = fmaf(yf, s0t, syK[k]);
        syyK[k] = fmaf(yf * yf, s0t, syyK[k]);
        float m = v.x; int j = 0;                 // strict '>' keeps first idx
        if (v.y > m) { m = v.y; j = 1; }
        if (v.z > m) { m = v.z; j = 2; }
        if (v.w > m) { m = v.w; j = 3; }
        if (m > mvK[k]) { mvK[k] = m; miK[k] = local + j; }
      }
    }
    asm volatile("s_waitcnt lgkmcnt(0)" ::: "memory");  // ds_reads complete
    __builtin_amdgcn_s_barrier();                // buf[cur] free to restage
  }

  // ---- epilogue: wave-reduce each owned channel (5 quantities) ----
  BP* bp = &ws->bp[blockIdx.x];
#pragma unroll
  for (int k = 0; k < 8; ++k) {
    float s0 = s0K[k], sy = syK[k], syy = syyK[k], mv = mvK[k];
    int mi = miK[k];
    for (int off = 32; off > 0; off >>= 1) {
      s0  += __shfl_down(s0,  off);
      sy  += __shfl_down(sy,  off);
      syy += __shfl_down(syy, off);
      const float ov = __shfl_down(mv, off);
      const int   oi = __shfl_down(mi, off);
      if (ov > mv || (ov == mv && oi < mi)) { mv = ov; mi = oi; }
    }
    if (l == 0) {
      const int c = w * 8 + k;
      bp->s0[c] = s0; bp->sy[c] = sy; bp->syy[c] = syy;
      bp->mx[c] = mv; bp->mi[c] = pb * YZ + mi;   // sample-voxel index
    }
  }

  // ---- block reduce A, B, vs ----
  for (int off = 32; off > 0; off >>= 1) {
    A  += __shfl_down(A,  off);
    Bv += __shfl_down(Bv, off);
    vs += __shfl_down(vs, off);
  }
  if (l == 0) { r3[w][0] = A; r3[w][1] = Bv; r3[w][2] = vs; }
  __syncthreads();
  if (t == 0) {
    ws->abv[blockIdx.x][0] = (r3[0][0] + r3[1][0]) + (r3[2][0] + r3[3][0]);
    ws->abv[blockIdx.x][1] = (r3[0][1] + r3[1][1]) + (r3[2][1] + r3[3][1]);
    ws->abv[blockIdx.x][2] = (r3[0][2] + r3[1][2]) + (r3[2][2] + r3[3][2]);
  }
}

// ---- finalize: thread = (b,c); merge 48 slab partials; assemble in f64 ----
__global__ __launch_bounds__(512) void k_fin(const Ws* __restrict__ ws,
                                             float* __restrict__ out) {
  const int t = threadIdx.x;
  const int b = t >> 5, c = t & 31;

  float mv = -FLT_MAX; int mi = INT_MAX;
  for (int k = 0; k < BPS; ++k) {
    const BP* p = &ws->bp[b * BPS + k];
    const float ov = p->mx[c]; const int oi = p->mi[c];
    if (ov > mv || (ov == mv && oi < mi)) { mv = ov; mi = oi; }
  }
  const double mx = (double)(mi / YZ);
  const double my = (double)((mi / NZ) % NY);
  const double mz = (double)(mi % NZ);

  double dis = 0.0, s0tot = 0.0;
  for (int k = 0; k < BPS; ++k) {
    const BP* p = &ws->bp[b * BPS + k];
    const double s0 = p->s0[c], sy = p->sy[c], syy = p->syy[c];
    const double dx = mx - (double)k;            // block k holds slab x == k
    dis += (dx * dx + my * my) * s0 - 2.0 * my * sy + syy;
    s0tot += s0;
  }
  dis += 2304.0 * (48.0 * mz * mz - 2256.0 * mz + 35720.0);

  double a = 0.0, bb2 = 0.0, vsum = 0.0;
  for (int i = t; i < GRID; i += 512) {
    a += ws->abv[i][0]; bb2 += ws->abv[i][1]; vsum += ws->abv[i][2];
  }

  for (int off = 32; off > 0; off >>= 1) {
    dis   += __shfl_down(dis,   off);
    s0tot += __shfl_down(s0tot, off);
    a     += __shfl_down(a,     off);
    bb2   += __shfl_down(bb2,   off);
    vsum  += __shfl_down(vsum,  off);
  }
  __shared__ double sd[8][5];
  const int wid = t >> 6;
  if ((t & 63) == 0) {
    sd[wid][0] = dis; sd[wid][1] = s0tot; sd[wid][2] = a;
    sd[wid][3] = bb2; sd[wid][4] = vsum;
  }
  __syncthreads();
  if (t == 0) {
    for (int q = 1; q < 8; ++q) {
      dis += sd[q][0]; s0tot += sd[q][1]; a += sd[q][2];
      bb2 += sd[q][3]; vsum += sd[q][4];
    }
    const double mgr = vsum / SUM_NUM;
    out[0] = (float)(dis / SUM_NUM);
    out[1] = (float)((a - 2.0 * mgr * bb2 + mgr * mgr * s0tot) / SUM_NUM);
  }
}

extern "C" void kernel_launch(void* const* d_in, const int* in_sizes, int n_in,
                              void* d_out, int out_size, void* d_ws, size_t ws_size,
                              hipStream_t stream) {
  const float* f = (const float*)d_in[0];
  Ws* ws = (Ws*)d_ws;
  float* out = (float*)d_out;
  hipLaunchKernelGGL(k_fused, dim3(GRID), dim3(256), 0, stream, f, ws);
  hipLaunchKernelGGL(k_fin,   dim3(1),    dim3(512), 0, stream, ws, out);
}